// Round 1
// baseline (259.682 us; speedup 1.0000x reference)
//
#include <hip/hip_runtime.h>
#include <math.h>

#define LMAX 30.0f

__device__ __forceinline__ float clip30(float x) {
    return fminf(fmaxf(x, -LMAX), LMAX);
}

// One block (64 threads = 1 wave) decodes one batch element.
// State (per block, LDS):
//   ch[128]        : channel LLRs (stage 7, identical across slots)
//   llr[16][132]   : per-slot LLR stages 0..6, stage s at offset (2^s - 1), len 2^s
//                    (row padded 127->132 to spread slots across LDS banks)
//   uh[16][7][2]   : bit-packed uhat, stages 0..6, 128 bits each (absolute positions)
//   pm/ptrv        : path metrics + list-position -> slot map
__global__ __launch_bounds__(64) void scl_kernel(const float* __restrict__ in,
                                                 float* __restrict__ out) {
    __shared__ float ch[128];
    __shared__ float llr[16][132];
    __shared__ unsigned long long uh[16][7][2];
    __shared__ float pm[16], pms[16];
    __shared__ int ptrv[16], ptrs[16];

    const int b = blockIdx.x;
    const int lane = threadIdx.x;

    // ---- init ----
    ch[lane]      = -in[(size_t)b * 128 + lane];
    ch[64 + lane] = -in[(size_t)b * 128 + 64 + lane];
    {
        unsigned long long* uz = &uh[0][0][0];
        for (int q = lane; q < 16 * 7 * 2; q += 64) uz[q] = 0ull;
    }
    if (lane < 16) {
        pm[lane] = (lane == 0 || lane == 8) ? 0.0f : LMAX;
        ptrv[lane] = lane;
    }
    __syncthreads();

    for (int i = 0; i < 128; ++i) {
        if (i == 0) {
            // full f descent: stages 7..1, start 0
            for (int s = 7; s >= 1; --s) {
                const int h = 1 << (s - 1);
                const int offs = (1 << s) - 1, offd = h - 1;
                for (int q = lane; q < (h << 4); q += 64) {
                    const int slot = q >> (s - 1), p = q & (h - 1);
                    float x, y;
                    if (s == 7) { x = ch[p]; y = ch[64 + p]; }
                    else        { x = llr[slot][offs + p]; y = llr[slot][offs + h + p]; }
                    x = clip30(x); y = clip30(y);
                    const float m = fminf(fabsf(x), fabsf(y));
                    const unsigned int sgn =
                        (__float_as_uint(x) ^ __float_as_uint(y)) & 0x80000000u;
                    llr[slot][offd + p] = __uint_as_float(__float_as_uint(m) | sgn);
                }
                __syncthreads();
            }
        } else {
            const int t = __builtin_ctz(i);
            // ---- combines at stages 1..t (lane == slot; same-lane chain, no
            //      barrier needed between stages) ----
            if (t > 0 && lane < 16) {
                for (int s = 1; s <= t; ++s) {
                    const int st = i - (1 << s);
                    const int h = 1 << (s - 1), len = 1 << s;
                    const int wi = st >> 6, o = st & 63;
                    const unsigned long long w = uh[lane][s - 1][wi];
                    const unsigned long long mh = (1ull << h) - 1ull;
                    const unsigned long long ul = (w >> o) & mh;
                    const unsigned long long ur = (w >> (o + h)) & mh;
                    const unsigned long long seg = (ul ^ ur) | (ur << h);
                    const unsigned long long ml =
                        (len == 64) ? ~0ull : ((1ull << len) - 1ull);
                    const unsigned long long W = uh[lane][s][wi];
                    uh[lane][s][wi] = (W & ~(ml << o)) | (seg << o);
                }
            }
            if (t > 0) __syncthreads();
            // ---- g at stage t+1, node start i - 2^t ----
            {
                const int s = t + 1;
                const int st = i - (1 << t);
                const int h = 1 << t;
                const int offs = (1 << s) - 1, offd = h - 1;
                for (int q = lane; q < (h << 4); q += 64) {
                    const int slot = q >> t, p = q & (h - 1);
                    float x, y;
                    if (s == 7) { x = ch[st + p]; y = ch[st + 64 + p]; }
                    else        { x = llr[slot][offs + p]; y = llr[slot][offs + h + p]; }
                    const int ap = st + p;
                    const unsigned long long w = uh[slot][s - 1][ap >> 6];
                    const int u = (int)((w >> (ap & 63)) & 1ull);
                    llr[slot][offd + p] = u ? (y - x) : (y + x);
                }
                __syncthreads();
            }
            // ---- f descent: stages t..1, node start i ----
            for (int s = t; s >= 1; --s) {
                const int h = 1 << (s - 1);
                const int offs = (1 << s) - 1, offd = h - 1;
                for (int q = lane; q < (h << 4); q += 64) {
                    const int slot = q >> (s - 1), p = q & (h - 1);
                    float x = llr[slot][offs + p];
                    float y = llr[slot][offs + h + p];
                    x = clip30(x); y = clip30(y);
                    const float m = fminf(fabsf(x), fabsf(y));
                    const unsigned int sgn =
                        (__float_as_uint(x) ^ __float_as_uint(y)) & 0x80000000u;
                    llr[slot][offd + p] = __uint_as_float(__float_as_uint(m) | sgn);
                }
                __syncthreads();
            }
        }

        // ---- leaf i ----
        const bool frozen = (i < 64);
        if (!frozen && lane >= 8 && lane < 16) {
            const int slot = ptrv[lane];
            uh[slot][0][i >> 6] |= (1ull << (i & 63));
        }
        if (lane < 16) {
            const int slot = ptrv[lane];
            const float l = clip30(llr[slot][0]);
            // u = 1 only for non-frozen upper list half; z = -(1-2u)*l
            const float z = (frozen || lane < 8) ? -l : l;
            // jax.nn.softplus(z) = max(z,0) + log1p(exp(-|z|))
            const float sp = fmaxf(z, 0.0f) + log1pf(expf(-fabsf(z)));
            pm[lane] += sp;
        }
        __syncthreads();
        if (!frozen) {
            // stable rank sort of 16 (pm, k) pairs
            if (lane < 16) {
                const float v = pm[lane];
                int r = 0;
                for (int j = 0; j < 16; ++j) {
                    const float pj = pm[j];
                    r += (pj < v) || (pj == v && j < lane);
                }
                pms[r] = v;
                ptrs[r] = ptrv[lane];
            }
            __syncthreads();
            // pm = [sorted[0..7], sorted[0..7]]; ptr = sorted; clone lo -> up
            if (lane < 16) {
                pm[lane] = pms[lane & 7];
                ptrv[lane] = ptrs[lane];
            }
            for (int q = lane; q < 8 * 128; q += 64) {
                const int pair = q >> 7, e = q & 127;
                if (e < 127) {
                    const int src = ptrs[pair], dst = ptrs[8 + pair];
                    llr[dst][e] = llr[src][e];
                }
            }
            for (int q = lane; q < 8 * 16; q += 64) {
                const int pair = q >> 4, wdi = q & 15;
                if (wdi < 14) {
                    const int src = ptrs[pair], dst = ptrs[8 + pair];
                    ((unsigned long long*)uh[dst])[wdi] =
                        ((unsigned long long*)uh[src])[wdi];
                }
            }
            __syncthreads();
        }
    }

    // ---- output: best path = ptrv[0] (pm sorted ascending at last leaf);
    //      info bits are positions 64..127 = word 1 of stage-0 bits ----
    const int best = ptrv[0];
    const unsigned long long w = uh[best][0][1];
    out[(size_t)b * 64 + lane] = (float)((w >> lane) & 1ull);
}

extern "C" void kernel_launch(void* const* d_in, const int* in_sizes, int n_in,
                              void* d_out, int out_size, void* d_ws, size_t ws_size,
                              hipStream_t stream) {
    const float* in = (const float*)d_in[0];
    float* out = (float*)d_out;
    const int batch = in_sizes[0] / 128;  // 2048
    scl_kernel<<<dim3(batch), dim3(64), 0, stream>>>(in, out);
}

// Round 2
// 134.015 us; speedup vs baseline: 1.9377x; 1.9377x over previous
//
#include <hip/hip_runtime.h>
#include <math.h>

#define LMAX 30.0f

__device__ __forceinline__ float clip30(float x) {
    return fminf(fmaxf(x, -LMAX), LMAX);
}
__device__ __forceinline__ float cnop(float x, float y) {
    x = clip30(x); y = clip30(y);
    const float m = fminf(fabsf(x), fabsf(y));
    const unsigned s = (__float_as_uint(x) ^ __float_as_uint(y)) & 0x80000000u;
    return __uint_as_float(__float_as_uint(m) | s);
}
__device__ __forceinline__ float splus(float z) {  // jax.nn.softplus(z)
    return fmaxf(z, 0.0f) + log1pf(expf(-fabsf(z)));
}
__device__ __forceinline__ unsigned long long bperm64(unsigned long long v, int srclane) {
    const int a = srclane << 2;
    const int lo = __builtin_amdgcn_ds_bpermute(a, (int)(unsigned)v);
    const int hi = __builtin_amdgcn_ds_bpermute(a, (int)(unsigned)(v >> 32));
    return ((unsigned long long)(unsigned)hi << 32) | (unsigned)lo;
}
__device__ __forceinline__ float gatherf(float v, int srclane) {
    return __int_as_float(__builtin_amdgcn_ds_bpermute(srclane << 2, __float_as_int(v)));
}
// single-wave block: DS ops are in-order per wave; this is a zero-cost
// compiler fence replacing __syncthreads()
#define WSYNC() do { __builtin_amdgcn_wave_barrier(); asm volatile("" ::: "memory"); } while (0)

// f at stage S: reads seg S (ch6 if S==6), writes seg S-1. Segment s at
// row offset (2^s - 1), node-local indexing. Row stride 68 (bank spread).
template<int S>
__device__ __forceinline__ void Fstep(float (*llr)[68], const float* ch6, int lane) {
    constexpr int h = 1 << (S - 1);
    constexpr int offS = (1 << S) - 1;
    constexpr int offD = h - 1;
    constexpr int W = 16 * h;
    #pragma unroll
    for (int r0 = 0; r0 < (W + 63) / 64; ++r0) {
        const int q = r0 * 64 + lane;
        if (W >= 64 || lane < W) {
            const int slot = q >> (S - 1);
            const int p = q & (h - 1);
            float x, y;
            if (S == 6) { x = ch6[p];               y = ch6[p + 32]; }
            else        { x = llr[slot][offS + p];  y = llr[slot][offS + h + p]; }
            llr[slot][offD + p] = cnop(x, y);
        }
    }
    WSYNC();
}

// g at stage S (ctz(ii)==S-1): u bits from uh stage S-1 word (gathered from
// owner lane == slot), node start = ii - 2^(S-1).
template<int S>
__device__ __forceinline__ void Gstep(int ii, float (*llr)[68], const float* ch6,
                                      unsigned long long uhword, int lane) {
    constexpr int h = 1 << (S - 1);
    constexpr int offS = (1 << S) - 1;
    constexpr int offD = h - 1;
    constexpr int W = 16 * h;
    const int o = (ii - h) - 64;  // node start - 64 (bit base in uh word)
    #pragma unroll
    for (int r0 = 0; r0 < (W + 63) / 64; ++r0) {
        const int q = r0 * 64 + lane;
        if (W >= 64 || lane < W) {
            const int slot = q >> (S - 1);
            const int p = q & (h - 1);
            const unsigned long long w = bperm64(uhword, slot);
            const int u = (int)((w >> (o + p)) & 1ULL);
            float x, y;
            if (S == 6) { x = ch6[o + p];           y = ch6[o + h + p]; }
            else        { x = llr[slot][offS + p];  y = llr[slot][offS + h + p]; }
            llr[slot][offD + p] = u ? (y - x) : (y + x);
        }
    }
    WSYNC();
}

__device__ __forceinline__ float F1reg(float (*llr)[68], int lane) {
    const int s0 = lane & 15;
    return cnop(llr[s0][1], llr[s0][2]);
}

// uhat combine at stage sA for node ending at ii: WB(stage sA) from WA(stage sA-1)
#define COMBINE(sA, WA, WB) do { \
    const int h2 = 1 << ((sA) - 1); \
    const int o2 = (ii - (1 << (sA))) - 64; \
    const unsigned long long mh = (1ULL << h2) - 1ULL; \
    const unsigned long long ul = ((WA) >> o2) & mh; \
    const unsigned long long ur = ((WA) >> (o2 + h2)) & mh; \
    (WB) |= ((ul ^ ur) | (ur << h2)) << o2; \
} while (0)

__global__ __launch_bounds__(64) void scl_kernel(const float* __restrict__ in,
                                                 float* __restrict__ out) {
    __shared__ float llr[16][68];   // per-slot segs 1..5 at offsets 1..62
    __shared__ float ch6[64];       // shared stage-6 right-subtree llr (u=0 g)
    __shared__ float sp64[64];      // frozen-half softplus terms

    const int b = blockIdx.x;
    const int lane = threadIdx.x;

    const float a = -in[(size_t)b * 128 + lane];
    const float c = -in[(size_t)b * 128 + 64 + lane];
    ch6[lane] = a + c;

    // ---- frozen half (leaves 0..63): all paths identical, u == 0 everywhere.
    // Leaf LLRs via butterfly: stage-7 f then h = 32..1 (f = cn, g = x + y).
    float v = cnop(a, c);
    #pragma unroll
    for (int k = 5; k >= 0; --k) {
        const int h = 1 << k;
        const float o = __shfl_xor(v, h);
        v = (lane & h) ? (o + v) : cnop(v, o);
    }
    sp64[lane] = splus(-clip30(v));
    WSYNC();

    // sequential pm accumulation, exact reference order (per-list-lane chain)
    float pmR = (lane == 0 || lane == 8) ? 0.0f : LMAX;
    #pragma unroll
    for (int j = 0; j < 64; ++j) pmR += sp64[j];

    int ptrR = lane & 15;
    unsigned long long uhw0 = 0, uhw1 = 0, uhw2 = 0, uhw3 = 0, uhw4 = 0, uhw5 = 0;

    // ---- info half (leaves 64..127) ----
    for (int ii = 64; ii < 128; ++ii) {
        const int t = __builtin_ctz(ii);  // 6 at ii==64

        // uhat combines for nodes ending at ii (register-only, per-slot lane)
        if (ii > 64) {
            if (t >= 1) COMBINE(1, uhw0, uhw1);
            if (t >= 2) COMBINE(2, uhw1, uhw2);
            if (t >= 3) COMBINE(3, uhw2, uhw3);
            if (t >= 4) COMBINE(4, uhw3, uhw4);
            if (t >= 5) COMBINE(5, uhw4, uhw5);
        }

        float l0R;
        switch (t) {
            case 0: {  // g at stage 1, register result (lane == slot)
                const int u = (int)((uhw0 >> (ii - 65)) & 1ULL);
                const int s0 = lane & 15;
                const float x = llr[s0][1], y = llr[s0][2];
                l0R = u ? (y - x) : (y + x);
            } break;
            case 1:
                Gstep<2>(ii, llr, ch6, uhw1, lane);
                l0R = F1reg(llr, lane);
                break;
            case 2:
                Gstep<3>(ii, llr, ch6, uhw2, lane);
                Fstep<2>(llr, ch6, lane);
                l0R = F1reg(llr, lane);
                break;
            case 3:
                Gstep<4>(ii, llr, ch6, uhw3, lane);
                Fstep<3>(llr, ch6, lane);
                Fstep<2>(llr, ch6, lane);
                l0R = F1reg(llr, lane);
                break;
            case 4:
                Gstep<5>(ii, llr, ch6, uhw4, lane);
                Fstep<4>(llr, ch6, lane);
                Fstep<3>(llr, ch6, lane);
                Fstep<2>(llr, ch6, lane);
                l0R = F1reg(llr, lane);
                break;
            case 5:
                Gstep<6>(ii, llr, ch6, uhw5, lane);
                Fstep<5>(llr, ch6, lane);
                Fstep<4>(llr, ch6, lane);
                Fstep<3>(llr, ch6, lane);
                Fstep<2>(llr, ch6, lane);
                l0R = F1reg(llr, lane);
                break;
            default:  // ii == 64: stage-7 g is ch6; pure f descent
                Fstep<6>(llr, ch6, lane);
                Fstep<5>(llr, ch6, lane);
                Fstep<4>(llr, ch6, lane);
                Fstep<3>(llr, ch6, lane);
                Fstep<2>(llr, ch6, lane);
                l0R = F1reg(llr, lane);
                break;
        }

        // ---- leaf ii (info): bit-set for upper list half (owner-slot lanes)
        {
            int setme = 0;
            #pragma unroll
            for (int k = 8; k < 16; ++k)
                setme |= (__shfl(ptrR, k) == lane) ? 1 : 0;
            if (setme) uhw0 |= (1ULL << (ii - 64));
        }
        // pm update (list-position lanes 0..15; others garbage, unused)
        {
            const float l = clip30(gatherf(l0R, ptrR));
            const float z = (lane & 8) ? l : -l;  // u=1 for list pos 8..15
            pmR += splus(z);
        }
        // stable rank sort of 16 (pm, listpos) pairs, register-only
        {
            const float vv = pmR;
            int r = 0;
            #pragma unroll
            for (int j = 0; j < 16; ++j) {
                const float pj = __shfl(pmR, j);
                r += ((pj < vv) || (pj == vv && j < lane)) ? 1 : 0;
            }
            float pmS = 0.0f; int ptrS = 0;
            if (lane < 16) {
                pmS = __int_as_float(
                    __builtin_amdgcn_ds_permute(r << 2, __float_as_int(vv)));
                ptrS = __builtin_amdgcn_ds_permute(r << 2, ptrR);
            }
            ptrR = (lane < 16) ? ptrS : ptrR;
            pmR = __shfl(pmS, lane & 7);  // pm[8..15] = pm[0..7]
        }
        // clone surviving paths into killed slots
        if (ii != 127) {
            // uhat clone: dst-slot lanes pull all 6 words from src-slot lane
            int srcidx = lane;
            #pragma unroll
            for (int pr = 0; pr < 8; ++pr) {
                const int dstslot = __shfl(ptrR, 8 + pr);
                const int srcslot = __shfl(ptrR, pr);
                srcidx = (lane == dstslot) ? srcslot : srcidx;
            }
            uhw0 = bperm64(uhw0, srcidx);
            uhw1 = bperm64(uhw1, srcidx);
            uhw2 = bperm64(uhw2, srcidx);
            uhw3 = bperm64(uhw3, srcidx);
            uhw4 = bperm64(uhw4, srcidx);
            uhw5 = bperm64(uhw5, srcidx);
            // llr clone: segment s live iff bit (s-1) of ii is 0
            #pragma unroll
            for (int s5 = 1; s5 <= 5; ++s5) {
                if (((ii >> (s5 - 1)) & 1) == 0) {
                    const int len = 1 << s5, off = len - 1;
                    const int items = 8 << s5;
                    #pragma unroll
                    for (int r0 = 0; r0 < (items + 63) / 64; ++r0) {
                        const int q = r0 * 64 + lane;
                        if (items >= 64 || lane < items) {
                            const int pair = q >> s5, e = q & (len - 1);
                            const int src = __shfl(ptrR, pair) & 15;
                            const int dst = __shfl(ptrR, 8 + pair) & 15;
                            llr[dst][off + e] = llr[src][off + e];
                        }
                    }
                }
            }
            WSYNC();
        }
    }

    // best path = list position 0 after final sort; info bits = uh word bits 0..63
    const int best = __shfl(ptrR, 0) & 15;
    const unsigned long long w = bperm64(uhw0, best);
    out[(size_t)b * 64 + lane] = (float)((w >> lane) & 1ULL);
}

extern "C" void kernel_launch(void* const* d_in, const int* in_sizes, int n_in,
                              void* d_out, int out_size, void* d_ws, size_t ws_size,
                              hipStream_t stream) {
    (void)n_in; (void)out_size; (void)d_ws; (void)ws_size;
    const float* in = (const float*)d_in[0];
    float* out = (float*)d_out;
    const int batch = in_sizes[0] / 128;  // 2048
    scl_kernel<<<dim3(batch), dim3(64), 0, stream>>>(in, out);
}

// Round 3
// 77.661 us; speedup vs baseline: 3.3438x; 1.7256x over previous
//
#include <hip/hip_runtime.h>
#include <math.h>

#define LMAX 30.0f

__device__ __forceinline__ float clip30(float x) {
    return fminf(fmaxf(x, -LMAX), LMAX);
}
__device__ __forceinline__ float cnop(float x, float y) {
    x = clip30(x); y = clip30(y);
    const float m = fminf(fabsf(x), fabsf(y));
    const unsigned s = (__float_as_uint(x) ^ __float_as_uint(y)) & 0x80000000u;
    return __uint_as_float(__float_as_uint(m) | s);
}
__device__ __forceinline__ float splus(float z) {  // jax.nn.softplus(z), bit-exact
    return fmaxf(z, 0.0f) + log1pf(expf(-fabsf(z)));
}
__device__ __forceinline__ unsigned long long bperm64(unsigned long long v, int srclane) {
    const int a = srclane << 2;
    const int lo = __builtin_amdgcn_ds_bpermute(a, (int)(unsigned)v);
    const int hi = __builtin_amdgcn_ds_bpermute(a, (int)(unsigned)(v >> 32));
    return ((unsigned long long)(unsigned)hi << 32) | (unsigned)lo;
}
__device__ __forceinline__ float gatherf(float v, int srclane) {
    return __int_as_float(__builtin_amdgcn_ds_bpermute(srclane << 2, __float_as_int(v)));
}
// single-wave block: DS ops in-order per wave; compiler fence only
#define WSYNC() do { __builtin_amdgcn_wave_barrier(); asm volatile("" ::: "memory"); } while (0)

// seg s: 32 rows (row = slot + 16*gen) of stride SEG_STR[s] floats at SEG_OFF[s]
constexpr int SEG_OFF[6] = {0, 0, 96, 256, 544, 1088};
constexpr int SEG_STR[6] = {0, 3, 5, 9, 17, 33};
// LL total = 1088 + 32*33 = 2144 floats

// f: reads seg S (ch6 if S==6, same-leaf gen row otherwise), writes seg S-1
template<int S>
__device__ __forceinline__ void Fstep(int ii, float* LL, const float* ch6,
                                      int& mapR, int lane) {
    constexpr int h = 1 << (S - 1);
    constexpr int W = 16 * h;
    constexpr int offD = SEG_OFF[S - 1], strD = SEG_STR[S - 1];
    const int genD = ((ii >> (S - 1)) & 1) << 4;
    const int genS = ((ii >> S) & 1) << 4;
    #pragma unroll
    for (int r0 = 0; r0 < (W + 63) / 64; ++r0) {
        const int q = r0 * 64 + lane;
        if (W >= 64 || lane < W) {
            const int slot = q >> (S - 1);
            const int p = q & (h - 1);
            float x, y;
            if constexpr (S == 6) {
                x = ch6[p]; y = ch6[32 + p];
            } else {
                const int rs = SEG_OFF[S] + (slot | genS) * SEG_STR[S];
                x = LL[rs + p]; y = LL[rs + h + p];
            }
            LL[offD + (slot | genD) * strD + p] = cnop(x, y);
        }
    }
    // record where seg S-1 now lives for this slot
    mapR = (mapR & ~(31 << (5 * (S - 2)))) | (((lane & 15) | genD) << (5 * (S - 2)));
    WSYNC();
}

// g: reads seg S cross-leaf via map (ch6 if S==6), u bits from uhw stage S-1
template<int S>
__device__ __forceinline__ void Gstep(int ii, float* LL, const float* ch6,
                                      unsigned long long uhword, int& mapR, int lane) {
    constexpr int h = 1 << (S - 1);
    constexpr int W = 16 * h;
    constexpr int offD = SEG_OFF[S - 1], strD = SEG_STR[S - 1];
    const int genD = ((ii >> (S - 1)) & 1) << 4;
    const int o = (ii - h) - 64;
    #pragma unroll
    for (int r0 = 0; r0 < (W + 63) / 64; ++r0) {
        const int q = r0 * 64 + lane;
        if (W >= 64 || lane < W) {
            const int slot = q >> (S - 1);
            const int p = q & (h - 1);
            const unsigned long long w = bperm64(uhword, slot);
            const int u = (int)((w >> (o + p)) & 1ULL);
            float x, y;
            if constexpr (S == 6) {
                x = ch6[o + p]; y = ch6[o + h + p];
            } else {
                const int mg = __builtin_amdgcn_ds_bpermute(slot << 2, mapR);
                const int row = (mg >> (5 * (S - 1))) & 31;
                const int rs = SEG_OFF[S] + row * SEG_STR[S];
                x = LL[rs + p]; y = LL[rs + h + p];
            }
            LL[offD + (slot | genD) * strD + p] = u ? (y - x) : (y + x);
        }
    }
    mapR = (mapR & ~(31 << (5 * (S - 2)))) | (((lane & 15) | genD) << (5 * (S - 2)));
    WSYNC();
}

__device__ __forceinline__ float F1reg(int ii, const float* LL, int lane) {
    const int row = (lane & 15) | (((ii >> 1) & 1) << 4);
    const int bo = row * 3;  // SEG_OFF[1]==0, SEG_STR[1]==3
    return cnop(LL[bo], LL[bo + 1]);
}

#define COMBINE(sA, WA, WB) do { \
    const int h2 = 1 << ((sA) - 1); \
    const int o2 = (ii - (1 << (sA))) - 64; \
    const unsigned long long mh = (1ULL << h2) - 1ULL; \
    const unsigned long long ul = ((WA) >> o2) & mh; \
    const unsigned long long ur = ((WA) >> (o2 + h2)) & mh; \
    (WB) |= ((ul ^ ur) | (ur << h2)) << o2; \
} while (0)

__global__ __launch_bounds__(64) void scl_kernel(const float* __restrict__ in,
                                                 float* __restrict__ out) {
    __shared__ float LL[2144];
    __shared__ float ch6[64];

    const int b = blockIdx.x;
    const int lane = threadIdx.x;

    const float a = -in[(size_t)b * 128 + lane];
    const float c = -in[(size_t)b * 128 + 64 + lane];
    ch6[lane] = a + c;
    WSYNC();

    // ---- frozen half: all paths identical, u==0; butterfly for leaf LLRs
    float v = cnop(a, c);
    #pragma unroll
    for (int k = 5; k >= 0; --k) {
        const int h = 1 << k;
        const float o = __shfl_xor(v, h);
        v = (lane & h) ? (o + v) : cnop(v, o);
    }
    const float sp = splus(-clip30(v));
    float pmR = (lane == 0 || lane == 8) ? 0.0f : LMAX;
    #pragma unroll
    for (int j = 0; j < 64; ++j)
        pmR += __uint_as_float((unsigned)__builtin_amdgcn_readlane(__float_as_int(sp), j));

    int posR = lane;     // slot -> list position (bijection, lanes 0..15)
    int mapR = 0;        // 5x5-bit: physical row of segs 1..5 for this slot
    int sbr = 0;         // slot-by-rank (valid lanes 0..15 after each sort)
    unsigned long long uhw0 = 0, uhw1 = 0, uhw2 = 0, uhw3 = 0, uhw4 = 0, uhw5 = 0;

    #pragma unroll 1
    for (int ie = 64; ie < 128; ie += 2) {
        // ================= even leaf ie (t >= 1) =================
        {
            const int ii = ie;
            const int t = __builtin_ctz(ii);
            if (ii > 64) {
                COMBINE(1, uhw0, uhw1);
                if (t >= 2) COMBINE(2, uhw1, uhw2);
                if (t >= 3) COMBINE(3, uhw2, uhw3);
                if (t >= 4) COMBINE(4, uhw3, uhw4);
                if (t >= 5) COMBINE(5, uhw4, uhw5);
            }
            float l0R;
            switch (t) {
                case 1:
                    Gstep<2>(ii, LL, ch6, uhw1, mapR, lane);
                    l0R = F1reg(ii, LL, lane);
                    break;
                case 2:
                    Gstep<3>(ii, LL, ch6, uhw2, mapR, lane);
                    Fstep<2>(ii, LL, ch6, mapR, lane);
                    l0R = F1reg(ii, LL, lane);
                    break;
                case 3:
                    Gstep<4>(ii, LL, ch6, uhw3, mapR, lane);
                    Fstep<3>(ii, LL, ch6, mapR, lane);
                    Fstep<2>(ii, LL, ch6, mapR, lane);
                    l0R = F1reg(ii, LL, lane);
                    break;
                case 4:
                    Gstep<5>(ii, LL, ch6, uhw4, mapR, lane);
                    Fstep<4>(ii, LL, ch6, mapR, lane);
                    Fstep<3>(ii, LL, ch6, mapR, lane);
                    Fstep<2>(ii, LL, ch6, mapR, lane);
                    l0R = F1reg(ii, LL, lane);
                    break;
                case 5:
                    Gstep<6>(ii, LL, ch6, uhw5, mapR, lane);
                    Fstep<5>(ii, LL, ch6, mapR, lane);
                    Fstep<4>(ii, LL, ch6, mapR, lane);
                    Fstep<3>(ii, LL, ch6, mapR, lane);
                    Fstep<2>(ii, LL, ch6, mapR, lane);
                    l0R = F1reg(ii, LL, lane);
                    break;
                default:  // ii == 64: stage-7 g == ch6; pure f descent
                    Fstep<6>(ii, LL, ch6, mapR, lane);
                    Fstep<5>(ii, LL, ch6, mapR, lane);
                    Fstep<4>(ii, LL, ch6, mapR, lane);
                    Fstep<3>(ii, LL, ch6, mapR, lane);
                    Fstep<2>(ii, LL, ch6, mapR, lane);
                    l0R = F1reg(ii, LL, lane);
                    break;
            }
            // ---- leaf (info) ----
            const int u = (posR >= 8) ? 1 : 0;
            if (u) uhw0 |= (1ULL << (ii - 64));
            const float l = clip30(l0R);
            pmR += splus(u ? l : -l);
            const unsigned long long key =
                ((unsigned long long)__float_as_uint(pmR) << 32) | (unsigned)posR;
            int r = 0;
            #pragma unroll
            for (int j = 0; j < 16; ++j) {
                const unsigned hj = (unsigned)__builtin_amdgcn_readlane(__float_as_int(pmR), j);
                const unsigned lj = (unsigned)__builtin_amdgcn_readlane(posR, j);
                const unsigned long long kj = ((unsigned long long)hj << 32) | lj;
                r += (kj < key) ? 1 : 0;
            }
            r = (lane < 16) ? r : lane;
            sbr = __builtin_amdgcn_ds_permute(r << 2, lane);
            posR = r;
            {
                const int srcUp = __builtin_amdgcn_ds_bpermute((r - 8) << 2, sbr);
                const int srcidx = (lane < 16 && r >= 8) ? srcUp : lane;
                pmR = gatherf(pmR, srcidx);
                mapR = __builtin_amdgcn_ds_bpermute(srcidx << 2, mapR);
                uhw0 = bperm64(uhw0, srcidx);
                if ((ii >> 1) & 1) uhw1 = bperm64(uhw1, srcidx);
                if ((ii >> 2) & 1) uhw2 = bperm64(uhw2, srcidx);
                if ((ii >> 3) & 1) uhw3 = bperm64(uhw3, srcidx);
                if ((ii >> 4) & 1) uhw4 = bperm64(uhw4, srcidx);
                // uhw5: never live across leaves
            }
        }
        // ================= odd leaf ie+1 (t == 0) =================
        {
            const int ii = ie + 1;
            // g at stage 1 in registers: seg 1 via own map row, u from own uhw0
            const int row = mapR & 31;
            const int bo = row * 3;
            const float x = LL[bo], y = LL[bo + 1];
            const int ug = (int)((uhw0 >> (ii - 65)) & 1ULL);
            const float l0R = ug ? (y - x) : (y + x);

            const int u = (posR >= 8) ? 1 : 0;
            if (u) uhw0 |= (1ULL << (ii - 64));
            const float l = clip30(l0R);
            pmR += splus(u ? l : -l);
            const unsigned long long key =
                ((unsigned long long)__float_as_uint(pmR) << 32) | (unsigned)posR;
            int r = 0;
            #pragma unroll
            for (int j = 0; j < 16; ++j) {
                const unsigned hj = (unsigned)__builtin_amdgcn_readlane(__float_as_int(pmR), j);
                const unsigned lj = (unsigned)__builtin_amdgcn_readlane(posR, j);
                const unsigned long long kj = ((unsigned long long)hj << 32) | lj;
                r += (kj < key) ? 1 : 0;
            }
            r = (lane < 16) ? r : lane;
            sbr = __builtin_amdgcn_ds_permute(r << 2, lane);
            posR = r;
            if (ii != 127) {
                const int srcUp = __builtin_amdgcn_ds_bpermute((r - 8) << 2, sbr);
                const int srcidx = (lane < 16 && r >= 8) ? srcUp : lane;
                pmR = gatherf(pmR, srcidx);
                mapR = __builtin_amdgcn_ds_bpermute(srcidx << 2, mapR);
                uhw0 = bperm64(uhw0, srcidx);
                if ((ii >> 1) & 1) uhw1 = bperm64(uhw1, srcidx);
                if ((ii >> 2) & 1) uhw2 = bperm64(uhw2, srcidx);
                if ((ii >> 3) & 1) uhw3 = bperm64(uhw3, srcidx);
                if ((ii >> 4) & 1) uhw4 = bperm64(uhw4, srcidx);
            }
        }
    }

    // best = slot ranked 0 at the final sort; info bits = uhw0 bits 0..63
    const int best = __builtin_amdgcn_readlane(sbr, 0);
    const unsigned wlo = (unsigned)__builtin_amdgcn_readlane((int)(unsigned)uhw0, best);
    const unsigned whi = (unsigned)__builtin_amdgcn_readlane((int)(unsigned)(uhw0 >> 32), best);
    const unsigned long long w = ((unsigned long long)whi << 32) | wlo;
    out[(size_t)b * 64 + lane] = (float)((w >> lane) & 1ULL);
}

extern "C" void kernel_launch(void* const* d_in, const int* in_sizes, int n_in,
                              void* d_out, int out_size, void* d_ws, size_t ws_size,
                              hipStream_t stream) {
    (void)n_in; (void)out_size; (void)d_ws; (void)ws_size;
    const float* in = (const float*)d_in[0];
    float* out = (float*)d_out;
    const int batch = in_sizes[0] / 128;  // 2048
    scl_kernel<<<dim3(batch), dim3(64), 0, stream>>>(in, out);
}